// Round 5
// baseline (999.933 us; speedup 1.0000x reference)
//
#include <hip/hip_runtime.h>

#define NN 50000
#define NE 400000
#define DIM 256
#define HID 512
#define NL 5
#define BN_EPS 1e-5f
#define NB_SCAN 196   // ceil(NN/256)

typedef float float4v __attribute__((ext_vector_type(4)));
typedef _Float16 half8 __attribute__((ext_vector_type(8)));
typedef _Float16 half4v __attribute__((ext_vector_type(4)));

__device__ __forceinline__ void gl_lds16(const void* g, void* l) {
    __builtin_amdgcn_global_load_lds((__attribute__((address_space(1))) void*)g,
                                     (__attribute__((address_space(3))) void*)l, 16, 0, 0);
}

// ---------------- setup kernels ----------------

__global__ void k_zero(int* p, int n) {
    int i = blockIdx.x * blockDim.x + threadIdx.x;
    if (i < n) p[i] = 0;
}

__global__ void k_x2h(const float* __restrict__ x, _Float16* __restrict__ xh) {
    int i = blockIdx.x * blockDim.x + threadIdx.x;
    if (i >= NN * DIM / 4) return;
    float4 v = ((const float4*)x)[i];
    half4v o;
    o.x = (_Float16)v.x; o.y = (_Float16)v.y; o.z = (_Float16)v.z; o.w = (_Float16)v.w;
    ((half4v*)xh)[i] = o;
}

// C[l][a*3+b][c] = E1[l][a][c] + E2[l][b][c]
__global__ void k_ctab(const float* __restrict__ E1, const float* __restrict__ E2,
                       float* __restrict__ C) {
    int b = blockIdx.x;            // 0..44
    int l = b / 9, ab = b % 9;
    int a = ab / 3, bb = ab % 3;
    int c = threadIdx.x;
    C[(size_t)b * DIM + c] = E1[(size_t)(l * 6 + a) * DIM + c] + E2[(size_t)(l * 3 + bb) * DIM + c];
}

__global__ void k_hist(const int* __restrict__ ei, int* __restrict__ counts) {
    int e = blockIdx.x * blockDim.x + threadIdx.x;
    if (e < NE) atomicAdd(&counts[ei[NE + e]], 1);
}

// ---- multi-block coalesced exclusive scan of counts -> row_ptr/cursor ----
__global__ void k_bsum(const int* __restrict__ counts, int* __restrict__ bsum) {
    __shared__ int s[256];
    int t = threadIdx.x;
    int i = blockIdx.x * 256 + t;
    s[t] = (i < NN) ? counts[i] : 0;
    __syncthreads();
    for (int off = 128; off > 0; off >>= 1) {
        if (t < off) s[t] += s[t + off];
        __syncthreads();
    }
    if (t == 0) bsum[blockIdx.x] = s[0];
}

__global__ void k_bscan(const int* __restrict__ bsum, int* __restrict__ bofs) {
    __shared__ int s[256];
    int t = threadIdx.x;
    int v = (t < NB_SCAN) ? bsum[t] : 0;
    s[t] = v;
    __syncthreads();
    for (int off = 1; off < 256; off <<= 1) {
        int u = (t >= off) ? s[t - off] : 0;
        __syncthreads();
        s[t] += u;
        __syncthreads();
    }
    if (t < NB_SCAN) bofs[t] = s[t] - v;
}

__global__ void k_scatterptr(const int* __restrict__ counts, const int* __restrict__ bofs,
                             int* __restrict__ row_ptr, int* __restrict__ cursor) {
    __shared__ int s[256];
    int t = threadIdx.x;
    int i = blockIdx.x * 256 + t;
    int v = (i < NN) ? counts[i] : 0;
    s[t] = v;
    __syncthreads();
    for (int off = 1; off < 256; off <<= 1) {
        int u = (t >= off) ? s[t - off] : 0;
        __syncthreads();
        s[t] += u;
        __syncthreads();
    }
    if (i < NN) {
        int ex = bofs[blockIdx.x] + s[t] - v;
        row_ptr[i] = ex;
        cursor[i] = ex;
    }
    if (i == NN - 1) row_ptr[NN] = NE;
}

// fill CSR src list + per-node attr-combo counts (attrs identical across layers)
__global__ void k_fill(const int* __restrict__ ei, const int* __restrict__ ea,
                       int* __restrict__ cursor, int* __restrict__ srcs,
                       int* __restrict__ cnt9) {
    int e = blockIdx.x * blockDim.x + threadIdx.x;
    if (e >= NE) return;
    int src = ei[e];
    int dst = ei[NE + e];
    int a = ea[2 * e];
    int b = ea[2 * e + 1];
    int pos = atomicAdd(&cursor[dst], 1);
    srcs[pos] = src;
    atomicAdd(&cnt9[dst * 9 + a * 3 + b], 1);
}

// transpose + f16 convert: W [L][K][N] fp32 -> T [L][N][K] f16
__global__ void k_wt(const float* __restrict__ W, _Float16* __restrict__ T, int K, int N) {
    __shared__ float t[32][33];
    int l = blockIdx.z;
    int k0 = blockIdx.y * 32, n0 = blockIdx.x * 32;
    int tx = threadIdx.x, ty = threadIdx.y;   // (32,8)
    const float* Wl = W + (size_t)l * K * N;
    _Float16* Tl = T + (size_t)l * N * K;
    for (int d = 0; d < 32; d += 8)
        t[ty + d][tx] = Wl[(size_t)(k0 + ty + d) * N + n0 + tx];
    __syncthreads();
    for (int d = 0; d < 32; d += 8)
        Tl[(size_t)(n0 + ty + d) * K + k0 + tx] = (_Float16)t[tx][ty + d];
}

// ---------------- aggregation: one wave per node ----------------
// rows: f16 [NN][DIM]. If APPLY: row value = relu(rows*s + t) (BN affine fused).
// Edge-embedding sum folded into per-node attr counts (9 FMAs in epilogue).
template <bool APPLY>
__global__ __launch_bounds__(256) void k_agg(const _Float16* __restrict__ rows,
                                             const float* __restrict__ ss,
                                             const float* __restrict__ Cl,
                                             const int* __restrict__ row_ptr,
                                             const int* __restrict__ srcs,
                                             const int* __restrict__ cnt9,
                                             _Float16* __restrict__ aggh) {
    int node = (blockIdx.x * blockDim.x + threadIdx.x) >> 6;
    int lane = threadIdx.x & 63;
    if (node >= NN) return;
    int c = lane * 4;
    float s0 = 1.f, s1 = 1.f, s2 = 1.f, s3 = 1.f, t0 = 0.f, t1 = 0.f, t2 = 0.f, t3 = 0.f;
    if (APPLY) {
        s0 = ss[c]; s1 = ss[c + 1]; s2 = ss[c + 2]; s3 = ss[c + 3];
        t0 = ss[DIM + c]; t1 = ss[DIM + c + 1]; t2 = ss[DIM + c + 2]; t3 = ss[DIM + c + 3];
    }
    float ax = 0.f, ay = 0.f, az = 0.f, aw = 0.f;
#define ACC(hv)                                                   \
    do {                                                          \
        if (APPLY) {                                              \
            ax += fmaxf((float)(hv).x * s0 + t0, 0.f);            \
            ay += fmaxf((float)(hv).y * s1 + t1, 0.f);            \
            az += fmaxf((float)(hv).z * s2 + t2, 0.f);            \
            aw += fmaxf((float)(hv).w * s3 + t3, 0.f);            \
        } else {                                                  \
            ax += (float)(hv).x; ay += (float)(hv).y;             \
            az += (float)(hv).z; aw += (float)(hv).w;             \
        }                                                         \
    } while (0)

    {   // self row
        half4v sv = *(const half4v*)(rows + (size_t)node * DIM + c);
        ACC(sv);
    }
    int e0 = row_ptr[node], e1 = row_ptr[node + 1];
    int e = e0;
    for (; e + 4 <= e1; e += 4) {
        int i0 = srcs[e], i1 = srcs[e + 1], i2 = srcs[e + 2], i3 = srcs[e + 3];
        half4v h0 = *(const half4v*)(rows + (size_t)i0 * DIM + c);
        half4v h1 = *(const half4v*)(rows + (size_t)i1 * DIM + c);
        half4v h2 = *(const half4v*)(rows + (size_t)i2 * DIM + c);
        half4v h3 = *(const half4v*)(rows + (size_t)i3 * DIM + c);
        ACC(h0); ACC(h1); ACC(h2); ACC(h3);
    }
    for (; e < e1; ++e) {
        int i0 = srcs[e];
        half4v h0 = *(const half4v*)(rows + (size_t)i0 * DIM + c);
        ACC(h0);
    }
#undef ACC
    // edge-embedding epilogue: Sum_a cnt[a] * C[a]; self-loop uses combo 0
    const int* cn = cnt9 + (size_t)node * 9;
#pragma unroll
    for (int a = 0; a < 9; ++a) {
        float f = (float)(cn[a] + (a == 0 ? 1 : 0));
        float4 cv = *(const float4*)(Cl + (size_t)a * DIM + c);
        ax += f * cv.x;
        ay += f * cv.y;
        az += f * cv.z;
        aw += f * cv.w;
    }
    half4v o;
    o.x = (_Float16)ax; o.y = (_Float16)ay; o.z = (_Float16)az; o.w = (_Float16)aw;
    *(half4v*)(aggh + (size_t)node * DIM + c) = o;
}

// ---------------- fused MLP: Z = (relu(A@W1+b1))@W2 + b2, + BN stats ----------------
// 64-row tile per block, 256 threads (4 waves). LDS: full A tile 32KB + H chunk
// 16KB = 48KB -> 3 blocks/CU. Stage-1/stage-2 interleaved over four 128-col H
// chunks: wave computes its 32-col slice of H chunk, sync, all waves consume the
// chunk as stage-2 k-slice, sync. A staged once via global_load_lds (XOR-swizzled).
// Epilogue: bias+stats, Z via LDS (reusing ldsA) -> coalesced 16B stores.
__global__ __launch_bounds__(256, 3) void k_mlp(const _Float16* __restrict__ A,
                                                const _Float16* __restrict__ W1t,
                                                const float* __restrict__ b1,
                                                const _Float16* __restrict__ W2t,
                                                const float* __restrict__ b2,
                                                _Float16* __restrict__ Z,
                                                float* __restrict__ stats, int M) {
    __shared__ _Float16 ldsA[64 * 256];   // 32 KB full A tile (swizzled); reused as Z tile
    __shared__ _Float16 ldsH[64 * 128];   // 16 KB H chunk (swizzled)
    int tid = threadIdx.x;
    int w = tid >> 6, lane = tid & 63;
    int lm = lane & 15, lg = lane >> 4;
    int row0 = blockIdx.x * 64;

    // stage full A tile: rows are 32 16B-slots; LDS[row][slot] = A[row][slot ^ (row&7)]
    {
        int srow = lane >> 5;       // 0..1
        int slot = lane & 31;
#pragma unroll
        for (int j = 0; j < 8; ++j) {
            int cr = w * 16 + j * 2 + srow;
            int gr = min(row0 + cr, M - 1);
            int gk = (slot ^ (cr & 7)) * 8;
            gl_lds16(A + (size_t)gr * DIM + gk, ldsA + (w * 16 + j * 2) * 256);
        }
    }
    __syncthreads();

    float4v acc2[4][4];
    const float4v zero = {0.f, 0.f, 0.f, 0.f};
#pragma unroll
    for (int i = 0; i < 4; ++i)
#pragma unroll
        for (int j = 0; j < 4; ++j) acc2[i][j] = zero;

#pragma unroll
    for (int ch = 0; ch < 4; ++ch) {
        // ---- stage 1: wave computes H cols [ch*128 + w*32, +32) over full K ----
        float4v acc1[4][2];
#pragma unroll
        for (int i = 0; i < 4; ++i)
#pragma unroll
            for (int j = 0; j < 2; ++j) acc1[i][j] = zero;
#pragma unroll
        for (int kq = 0; kq < 8; ++kq) {
            half8 bf[2];
#pragma unroll
            for (int nt = 0; nt < 2; ++nt) {
                int n = ch * 128 + w * 32 + nt * 16 + lm;
                bf[nt] = *(const half8*)(W1t + (size_t)n * DIM + kq * 32 + lg * 8);
            }
            half8 af[4];
#pragma unroll
            for (int mt = 0; mt < 4; ++mt) {
                int m = mt * 16 + lm;
                int slot = kq * 4 + lg;
                af[mt] = *(const half8*)(ldsA + m * 256 + ((slot ^ (m & 7)) * 8));
            }
#pragma unroll
            for (int mt = 0; mt < 4; ++mt)
#pragma unroll
                for (int nt = 0; nt < 2; ++nt)
                    acc1[mt][nt] = __builtin_amdgcn_mfma_f32_16x16x32_f16(af[mt], bf[nt],
                                                                          acc1[mt][nt], 0, 0, 0);
        }
        // H(relu) -> ldsH (chunk-local cols 0..127, swizzled by row)
#pragma unroll
        for (int nt = 0; nt < 2; ++nt) {
            int hc = w * 32 + nt * 16 + lm;          // chunk-local col
            float bv = b1[ch * 128 + hc];
            int cs = hc >> 3, ci = hc & 7;
#pragma unroll
            for (int mt = 0; mt < 4; ++mt)
#pragma unroll
                for (int r = 0; r < 4; ++r) {
                    int row = mt * 16 + lg * 4 + r;
                    float v = fmaxf(acc1[mt][nt][r] + bv, 0.f);
                    ldsH[row * 128 + ((cs ^ (row & 7)) << 3) + ci] = (_Float16)v;
                }
        }
        __syncthreads();
        // ---- stage 2 partial: acc2 += Hchunk @ W2[ch*128:+128, :] ----
#pragma unroll
        for (int kq = 0; kq < 4; ++kq) {
            half8 bf[4];
#pragma unroll
            for (int nt = 0; nt < 4; ++nt) {
                int n = w * 64 + nt * 16 + lm;
                bf[nt] = *(const half8*)(W2t + (size_t)n * HID + ch * 128 + kq * 32 + lg * 8);
            }
            half8 af[4];
#pragma unroll
            for (int mt = 0; mt < 4; ++mt) {
                int m = mt * 16 + lm;
                int slot = kq * 4 + lg;
                af[mt] = *(const half8*)(ldsH + m * 128 + ((slot ^ (m & 7)) << 3));
            }
#pragma unroll
            for (int mt = 0; mt < 4; ++mt)
#pragma unroll
                for (int nt = 0; nt < 4; ++nt)
                    acc2[mt][nt] = __builtin_amdgcn_mfma_f32_16x16x32_f16(af[mt], bf[nt],
                                                                          acc2[mt][nt], 0, 0, 0);
        }
        __syncthreads();   // ldsH free for next chunk (also frees ldsA after last)
    }

    // ---------- epilogue: bias + stats + Z via LDS (reuse ldsA) ----------
    _Float16* ldsZ = ldsA;   // 64 x 256 f16, swizzled like staging
    float psum[4], psq[4];
#pragma unroll
    for (int nt = 0; nt < 4; ++nt) { psum[nt] = 0.f; psq[nt] = 0.f; }
#pragma unroll
    for (int nt = 0; nt < 4; ++nt) {
        int col = w * 64 + nt * 16 + lm;
        float bv = b2[col];
        int cs = col >> 3, ci = col & 7;
#pragma unroll
        for (int mt = 0; mt < 4; ++mt)
#pragma unroll
            for (int r = 0; r < 4; ++r) {
                int row = mt * 16 + lg * 4 + r;
                float v = acc2[mt][nt][r] + bv;
                if (row0 + row < M) {
                    psum[nt] += v;
                    psq[nt] += v * v;
                }
                ldsZ[row * 256 + ((cs ^ (row & 7)) << 3) + ci] = (_Float16)v;
            }
    }
#pragma unroll
    for (int nt = 0; nt < 4; ++nt) {
        psum[nt] += __shfl_xor(psum[nt], 16);
        psum[nt] += __shfl_xor(psum[nt], 32);
        psq[nt] += __shfl_xor(psq[nt], 16);
        psq[nt] += __shfl_xor(psq[nt], 32);
    }
    if (lg == 0) {
#pragma unroll
        for (int nt = 0; nt < 4; ++nt) {
            int chn = w * 64 + nt * 16 + lm;
            atomicAdd(&stats[chn], psum[nt]);
            atomicAdd(&stats[DIM + chn], psq[nt]);
        }
    }
    __syncthreads();
    // coalesced store: 2048 16B-slots, thread t -> slots t, t+256, ...
#pragma unroll
    for (int i = 0; i < 8; ++i) {
        int s = i * 256 + tid;
        int row = s >> 5, c16 = s & 31;
        if (row0 + row < M) {
            half8 v = *(const half8*)(ldsZ + row * 256 + ((c16 ^ (row & 7)) << 3));
            *(half8*)(Z + (size_t)(row0 + row) * DIM + c16 * 8) = v;
        }
    }
}

// ---------------- BatchNorm finalize (also re-zeros stats) + final output ----------------
__global__ void k_bnfin(float* __restrict__ stats, const float* __restrict__ gamma,
                        const float* __restrict__ beta, float* __restrict__ ss) {
    int c = threadIdx.x;
    float mu = stats[c] * (1.0f / NN);
    float var = stats[DIM + c] * (1.0f / NN) - mu * mu;
    float sc = gamma[c] / sqrtf(var + BN_EPS);
    ss[c] = sc;
    ss[DIM + c] = beta[c] - mu * sc;
    stats[c] = 0.f;
    stats[DIM + c] = 0.f;
}

__global__ void k_out(const _Float16* __restrict__ z, const float* __restrict__ ss,
                      float* __restrict__ out) {
    int i = blockIdx.x * blockDim.x + threadIdx.x;
    if (i >= NN * DIM / 4) return;
    int c4 = (i & (DIM / 4 - 1)) * 4;
    half4v v = ((const half4v*)z)[i];
    float4 o;
    o.x = (float)v.x * ss[c4] + ss[DIM + c4];
    o.y = (float)v.y * ss[c4 + 1] + ss[DIM + c4 + 1];
    o.z = (float)v.z * ss[c4 + 2] + ss[DIM + c4 + 2];
    o.w = (float)v.w * ss[c4 + 3] + ss[DIM + c4 + 3];
    ((float4*)out)[i] = o;
}

// ---------------- host launcher ----------------
extern "C" void kernel_launch(void* const* d_in, const int* in_sizes, int n_in,
                              void* d_out, int out_size, void* d_ws, size_t ws_size,
                              hipStream_t stream) {
    const float* x = (const float*)d_in[0];
    const int* ei = (const int*)d_in[1];
    const int* ea = (const int*)d_in[2];
    const float* W1 = (const float*)d_in[4];
    const float* b1 = (const float*)d_in[5];
    const float* W2 = (const float*)d_in[6];
    const float* b2 = (const float*)d_in[7];
    const float* E1 = (const float*)d_in[8];
    const float* E2 = (const float*)d_in[9];
    const float* gamma = (const float*)d_in[10];
    const float* beta = (const float*)d_in[11];
    float* out = (float*)d_out;

    char* w = (char*)d_ws;
    _Float16* xh = (_Float16*)w;   w += (size_t)NN * DIM * 2;
    _Float16* z = (_Float16*)w;    w += (size_t)NN * DIM * 2;
    _Float16* aggh = (_Float16*)w; w += (size_t)NN * DIM * 2;
    _Float16* W1t = (_Float16*)w;  w += (size_t)NL * DIM * HID * 2;
    _Float16* W2t = (_Float16*)w;  w += (size_t)NL * HID * DIM * 2;
    float* Ctab = (float*)w;       w += (size_t)NL * 9 * DIM * 4;
    float* stats = (float*)w;      w += 2 * DIM * 4;
    float* ss = (float*)w;         w += 2 * DIM * 4;
    int* row_ptr = (int*)w;        w += (size_t)(NN + 2) * 4;
    int* counts = (int*)w;         w += (size_t)NN * 4;
    int* cursor = (int*)w;         w += (size_t)NN * 4;
    int* bsum = (int*)w;           w += 256 * 4;
    int* bofs = (int*)w;           w += 256 * 4;
    int* srcs = (int*)w;           w += (size_t)NE * 4;
    int* cnt9 = (int*)w;           w += (size_t)NN * 9 * 4;

    // setup: f16 x, edge-combo tables, CSR by dst, attr counts, f16 weights^T
    k_zero<<<(NN + 255) / 256, 256, 0, stream>>>(counts, NN);
    k_zero<<<(NN * 9 + 255) / 256, 256, 0, stream>>>(cnt9, NN * 9);
    k_zero<<<2, 256, 0, stream>>>((int*)stats, 2 * DIM);
    k_x2h<<<(NN * DIM / 4 + 255) / 256, 256, 0, stream>>>(x, xh);
    k_ctab<<<NL * 9, 256, 0, stream>>>(E1, E2, Ctab);
    k_hist<<<(NE + 255) / 256, 256, 0, stream>>>(ei, counts);
    k_bsum<<<NB_SCAN, 256, 0, stream>>>(counts, bsum);
    k_bscan<<<1, 256, 0, stream>>>(bsum, bofs);
    k_scatterptr<<<NB_SCAN, 256, 0, stream>>>(counts, bofs, row_ptr, cursor);
    k_fill<<<(NE + 255) / 256, 256, 0, stream>>>(ei, ea, cursor, srcs, cnt9);
    {
        dim3 b(32, 8);
        dim3 g1(HID / 32, DIM / 32, NL);
        k_wt<<<g1, b, 0, stream>>>(W1, W1t, DIM, HID);
        dim3 g2(DIM / 32, HID / 32, NL);
        k_wt<<<g2, b, 0, stream>>>(W2, W2t, HID, DIM);
    }

    for (int l = 0; l < NL; ++l) {
        const float* Cl = Ctab + (size_t)l * 9 * DIM;
        if (l == 0)
            k_agg<false><<<(NN + 3) / 4, 256, 0, stream>>>(xh, ss, Cl, row_ptr, srcs, cnt9, aggh);
        else
            k_agg<true><<<(NN + 3) / 4, 256, 0, stream>>>(z, ss, Cl, row_ptr, srcs, cnt9, aggh);

        k_mlp<<<(NN + 63) / 64, 256, 0, stream>>>(aggh, W1t + (size_t)l * DIM * HID,
                                                  b1 + (size_t)l * HID,
                                                  W2t + (size_t)l * HID * DIM,
                                                  b2 + (size_t)l * DIM, z, stats, NN);

        k_bnfin<<<1, 256, 0, stream>>>(stats, gamma + (size_t)l * DIM, beta + (size_t)l * DIM, ss);
    }
    k_out<<<(NN * DIM / 4 + 255) / 256, 256, 0, stream>>>(z, ss, out);
}